// Round 6
// baseline (392.446 us; speedup 1.0000x reference)
//
#include <hip/hip_runtime.h>
#include <hip/hip_bf16.h>

// Problem constants
#define NB    4
#define NP    12          // P1 == P == 12
#define NN_   207
#define DM    128         // d_model
#define DHID  256
#define M_TOK 9936        // NB*NP*NN_
#define M_PADH 9984       // hbf padded rows (78*128)

typedef float        f32x4 __attribute__((ext_vector_type(4)));
typedef unsigned int u32x4 __attribute__((ext_vector_type(4)));
typedef __bf16       bf16x8 __attribute__((ext_vector_type(8)));

static __device__ __forceinline__ unsigned int pk_bf2(float a, float b) {
    __hip_bfloat16 ba = __float2bfloat16(a);
    __hip_bfloat16 bb = __float2bfloat16(b);
    unsigned short ua = *reinterpret_cast<unsigned short*>(&ba);
    unsigned short ub = *reinterpret_cast<unsigned short*>(&bb);
    return (unsigned int)ua | ((unsigned int)ub << 16);
}

// ---------------- fused prep kernel: W2->bf16 | meta (h->bf16, Qb) ----------------
// blocks [0,2048): cvt_w2; [2048,3290): meta
__global__ __launch_bounds__(256) void k_prep(const float* __restrict__ W2,
                                              unsigned short* __restrict__ W2b,
                                              const float* __restrict__ x,
                                              const float* __restrict__ ct,
                                              const float* __restrict__ W1,
                                              const float* __restrict__ b1,
                                              const float* __restrict__ b2,
                                              unsigned short* __restrict__ hbf,
                                              float* __restrict__ Qb) {
    __shared__ float sm[2112];
    const int t = threadIdx.x;
    const int bid = blockIdx.x;
    if (bid < 2048) {
        // ---- W2 fp32 -> bf16, 8 f32 per thread ----
        int i = bid * 256 + t;
        const f32x4* in = reinterpret_cast<const f32x4*>(W2);
        f32x4 v0 = in[2 * i], v1 = in[2 * i + 1];
        u32x4 o;
        o[0] = pk_bf2(v0[0], v0[1]);
        o[1] = pk_bf2(v0[2], v0[3]);
        o[2] = pk_bf2(v1[0], v1[1]);
        o[3] = pk_bf2(v1[2], v1[3]);
        reinterpret_cast<u32x4*>(W2b)[i] = o;
    } else {
        // ---- meta: h = relu(W1 ct + b1) -> bf16; Qb = b2-reshaped . x ----
        float* cts = sm;                // [8][128]
        float* xs  = sm + 1024;         // [8][128]
        const int b = bid - 2048;
        const int m0 = b * 8;
        {
            int tok = t >> 5, c4 = t & 31;
            *reinterpret_cast<f32x4*>(&cts[tok * 128 + c4 * 4]) =
                *reinterpret_cast<const f32x4*>(&ct[(size_t)(m0 + tok) * DM + c4 * 4]);
            *reinterpret_cast<f32x4*>(&xs[tok * 128 + c4 * 4]) =
                *reinterpret_cast<const f32x4*>(&x[(size_t)(m0 + tok) * DM + c4 * 4]);
        }
        __syncthreads();
        {   // h: thread t owns hidden unit j = t for 8 tokens
            const int j = t;
            const f32x4* w1r = reinterpret_cast<const f32x4*>(&W1[(size_t)j * DM]);
            float acc[8] = {0, 0, 0, 0, 0, 0, 0, 0};
            for (int c = 0; c < 32; ++c) {
                f32x4 wv = w1r[c];
                #pragma unroll
                for (int tok = 0; tok < 8; ++tok) {
                    f32x4 cv = *reinterpret_cast<const f32x4*>(&cts[tok * 128 + c * 4]);
                    acc[tok] += wv[0] * cv[0] + wv[1] * cv[1] + wv[2] * cv[2] + wv[3] * cv[3];
                }
            }
            float bb = b1[j];
            #pragma unroll
            for (int tok = 0; tok < 8; ++tok) {
                float hv = fmaxf(acc[tok] + bb, 0.0f);
                __hip_bfloat16 hb = __float2bfloat16(hv);
                hbf[(size_t)(m0 + tok) * DHID + j] = *reinterpret_cast<unsigned short*>(&hb);
            }
        }
        {   // Qb: thread owns output o = t&127 for 4 tokens
            const int o = t & 127;
            const int tg = (t >> 7) * 4;
            const f32x4* b2r = reinterpret_cast<const f32x4*>(&b2[(size_t)o * DM]);
            float acc[4] = {0, 0, 0, 0};
            for (int c = 0; c < 32; ++c) {
                f32x4 wv = b2r[c];
                #pragma unroll
                for (int tt = 0; tt < 4; ++tt) {
                    f32x4 xv = *reinterpret_cast<const f32x4*>(&xs[(tg + tt) * 128 + c * 4]);
                    acc[tt] += wv[0] * xv[0] + wv[1] * xv[1] + wv[2] * xv[2] + wv[3] * xv[3];
                }
            }
            #pragma unroll
            for (int tt = 0; tt < 4; ++tt)
                Qb[(size_t)(m0 + tg + tt) * DM + o] = acc[tt];
        }
    }
}

// ---------------- kernel: G-form GEMM + in-register x-contraction ----------------
// G[od, m] = sum_j W2b[od, j] * hbf[m, j]   (bf16 MFMA, M-side = od, N-side = m, K = 256)
// Q[m, o]  = sum_d xin[m, d] * G[o*128+d, m]   (f32 epilogue in registers)
// Block: 128 m x 256 od; 4 waves in 2x2 (wm, wo): wave = 64 m (4 nf) x 128 od (8 mf).
// Both operands are 16B-contiguous global loads (j-contiguous rows); no LDS, no barriers,
// no per-step VALU (k folds into load imm offsets under full unroll).
// Grid: 78 m-blocks * 64 od-blocks = 4992; odb = bid&63 -> per-XCD 1MB W2b slice in L2.
__global__ __launch_bounds__(256, 2) void k_gemm(const unsigned short* __restrict__ W2b,
                                                 const unsigned short* __restrict__ hbf,
                                                 const float* __restrict__ xin,
                                                 float* __restrict__ Qp) {
    const int t = threadIdx.x;
    const int odb = blockIdx.x & 63;
    const int mb  = blockIdx.x >> 6;         // 0..77
    const int w   = t >> 6;
    const int wo  = w >> 1, wm = w & 1;
    const int l   = t & 63;
    const int lr  = l & 15, lg = l >> 4;
    const int m0  = mb * 128 + wm * 64;      // wave m base (4 frags of 16)
    const int od0 = odb * 256 + wo * 128;    // wave od base (8 frags of 16)

    // ushort offsets, constant through k-loop (k*32 folds into imm offset)
    unsigned int offA[8], offB[4];
    #pragma unroll
    for (int mf = 0; mf < 8; ++mf) offA[mf] = (unsigned)(od0 + mf * 16 + lr) * 256u + lg * 8u;
    #pragma unroll
    for (int nf = 0; nf < 4; ++nf) offB[nf] = (unsigned)(m0 + nf * 16 + lr) * 256u + lg * 8u;

    f32x4 acc[8][4];
    #pragma unroll
    for (int mf = 0; mf < 8; ++mf)
        #pragma unroll
        for (int nf = 0; nf < 4; ++nf) acc[mf][nf] = (f32x4)(0.0f);

    bf16x8 Af[2][8], Bf[2][4];
    #pragma unroll
    for (int mf = 0; mf < 8; ++mf) Af[0][mf] = *reinterpret_cast<const bf16x8*>(W2b + offA[mf]);
    #pragma unroll
    for (int nf = 0; nf < 4; ++nf) Bf[0][nf] = *reinterpret_cast<const bf16x8*>(hbf + offB[nf]);

    #pragma unroll
    for (int k = 0; k < 8; ++k) {
        const int c = k & 1;
        if (k < 7) {   // 1-deep register prefetch of k+1 (offsets compile-time)
            #pragma unroll
            for (int mf = 0; mf < 8; ++mf)
                Af[c ^ 1][mf] = *reinterpret_cast<const bf16x8*>(W2b + offA[mf] + (k + 1) * 32);
            #pragma unroll
            for (int nf = 0; nf < 4; ++nf)
                Bf[c ^ 1][nf] = *reinterpret_cast<const bf16x8*>(hbf + offB[nf] + (k + 1) * 32);
        }
        __builtin_amdgcn_s_setprio(1);
        #pragma unroll
        for (int mf = 0; mf < 8; ++mf)
            #pragma unroll
            for (int nf = 0; nf < 4; ++nf)
                acc[mf][nf] = __builtin_amdgcn_mfma_f32_16x16x32_bf16(Af[c][mf], Bf[c][nf],
                                                                      acc[mf][nf], 0, 0, 0);
        __builtin_amdgcn_s_setprio(0);
    }

    // epilogue: D[od][m]: col(m)=lane&15, row(od within frag)=(lane>>4)*4+r
    // d = mf*16 + lg*4 + r ; o = od0>>7 ; Q[m,o] = sum_d x[m,d]*G
    const int o = od0 >> 7;                  // = odb*2 + wo
    #pragma unroll
    for (int nf = 0; nf < 4; ++nf) {
        int m = m0 + nf * 16 + lr;
        int mx = m < M_TOK ? m : (M_TOK - 1);
        const f32x4* xr = reinterpret_cast<const f32x4*>(&xin[(size_t)mx * DM]);
        float qs = 0.0f;
        #pragma unroll
        for (int mf = 0; mf < 8; ++mf) {
            f32x4 xv = xr[mf * 4 + lg];
            qs += xv[0] * acc[mf][nf][0] + xv[1] * acc[mf][nf][1]
                + xv[2] * acc[mf][nf][2] + xv[3] * acc[mf][nf][3];
        }
        qs += __shfl_xor(qs, 16, 64);
        qs += __shfl_xor(qs, 32, 64);
        if (l < 16 && m < M_TOK) Qp[(size_t)m * DM + o] = qs;
    }
}

// ---------------- attention + W_out + residual + layernorm ----------------
__global__ __launch_bounds__(256) void k_attn(const float* __restrict__ Qp,
                                              const float* __restrict__ Qb,
                                              const float* __restrict__ Kenc,
                                              const float* __restrict__ Venc,
                                              const float* __restrict__ xin,
                                              const float* __restrict__ Wout,
                                              const float* __restrict__ gamma,
                                              const float* __restrict__ beta,
                                              float* __restrict__ out) {
    __shared__ float Qs[12][132];
    __shared__ float Ks[12][132];
    __shared__ float Vs[12][132];
    __shared__ float Ss[12][12][8];
    __shared__ float Os[12][132];
    __shared__ float Ws[64][132];
    const int t = threadIdx.x;
    const int b = blockIdx.x / NN_;
    const int n = blockIdx.x % NN_;

    for (int e = t; e < 384; e += 256) {
        int row = e >> 5, c4 = e & 31;
        size_t mrow = (size_t)(b * NP + row) * NN_ + n;
        f32x4 q = *reinterpret_cast<const f32x4*>(&Qb[mrow * DM + c4 * 4]);
        q += *reinterpret_cast<const f32x4*>(&Qp[mrow * DM + c4 * 4]);
        *reinterpret_cast<f32x4*>(&Qs[row][c4 * 4]) = q;
        *reinterpret_cast<f32x4*>(&Ks[row][c4 * 4]) =
            *reinterpret_cast<const f32x4*>(&Kenc[mrow * DM + c4 * 4]);
        *reinterpret_cast<f32x4*>(&Vs[row][c4 * 4]) =
            *reinterpret_cast<const f32x4*>(&Venc[mrow * DM + c4 * 4]);
    }
    __syncthreads();
    if (t < 144) {
        int q = t / 12, p = t % 12;
        #pragma unroll
        for (int hh = 0; hh < 8; ++hh) {
            const f32x4* qv = reinterpret_cast<const f32x4*>(&Qs[q][hh * 16]);
            const f32x4* kv = reinterpret_cast<const f32x4*>(&Ks[p][hh * 16]);
            float s = 0.0f;
            #pragma unroll
            for (int c = 0; c < 4; ++c) {
                f32x4 a = qv[c], bb = kv[c];
                s += a[0] * bb[0] + a[1] * bb[1] + a[2] * bb[2] + a[3] * bb[3];
            }
            Ss[q][p][hh] = s * 0.25f;
        }
    }
    __syncthreads();
    if (t < 96) {
        int q = t >> 3, hh = t & 7;
        float mx = -1e30f;
        #pragma unroll
        for (int p = 0; p < 12; ++p) mx = fmaxf(mx, Ss[q][p][hh]);
        float ev[12]; float sum = 0.0f;
        #pragma unroll
        for (int p = 0; p < 12; ++p) { ev[p] = __expf(Ss[q][p][hh] - mx); sum += ev[p]; }
        float inv = 1.0f / sum;
        #pragma unroll
        for (int p = 0; p < 12; ++p) Ss[q][p][hh] = ev[p] * inv;
    }
    __syncthreads();
    #pragma unroll
    for (int i = 0; i < 6; ++i) {
        int e = i * 256 + t;
        int q = e >> 7, hk = e & 127, hh = hk >> 4;
        float acc = 0.0f;
        #pragma unroll
        for (int p = 0; p < 12; ++p) acc += Ss[q][p][hh] * Vs[p][hk];
        Os[q][hk] = acc;
    }
    __syncthreads();
    for (int half = 0; half < 2; ++half) {
        #pragma unroll
        for (int i = 0; i < 8; ++i) {
            int e = i * 256 + t;
            int row = e >> 5, c4 = e & 31;
            *reinterpret_cast<f32x4*>(&Ws[row][c4 * 4]) =
                *reinterpret_cast<const f32x4*>(&Wout[(size_t)(half * 64 + row) * DM + c4 * 4]);
        }
        __syncthreads();
        #pragma unroll
        for (int i = 0; i < 3; ++i) {
            int idx = i * 256 + t;
            int o = idx / 12, q = idx % 12;
            const f32x4* ov = reinterpret_cast<const f32x4*>(&Os[q][0]);
            const f32x4* wv = reinterpret_cast<const f32x4*>(&Ws[o][0]);
            float s = 0.0f;
            #pragma unroll
            for (int c = 0; c < 32; ++c) {
                f32x4 a = ov[c], bb = wv[c];
                s += a[0] * bb[0] + a[1] * bb[1] + a[2] * bb[2] + a[3] * bb[3];
            }
            int oo = half * 64 + o;
            size_t mrow = (size_t)(b * NP + q) * NN_ + n;
            Qs[q][oo] = s + xin[mrow * DM + oo];
        }
        __syncthreads();
    }
    const int wv_ = t >> 6, l = t & 63;
    for (int rq = wv_; rq < 12; rq += 4) {
        float v0 = Qs[rq][l], v1 = Qs[rq][l + 64];
        float s = v0 + v1, ss = v0 * v0 + v1 * v1;
        #pragma unroll
        for (int msk = 1; msk < 64; msk <<= 1) {
            s += __shfl_xor(s, msk, 64);
            ss += __shfl_xor(ss, msk, 64);
        }
        float mu = s * (1.0f / 128.0f);
        float var = ss * (1.0f / 128.0f) - mu * mu;
        float rs = rsqrtf(var + 1e-5f);
        size_t mrow = (size_t)(b * NP + rq) * NN_ + n;
        out[mrow * DM + l]      = (v0 - mu) * rs * gamma[l] + beta[l];
        out[mrow * DM + l + 64] = (v1 - mu) * rs * gamma[l + 64] + beta[l + 64];
    }
}

// ---------------- launcher ----------------
extern "C" void kernel_launch(void* const* d_in, const int* in_sizes, int n_in,
                              void* d_out, int out_size, void* d_ws, size_t ws_size,
                              hipStream_t stream) {
    const float* xin   = (const float*)d_in[0];
    const float* Kenc  = (const float*)d_in[1];
    const float* Venc  = (const float*)d_in[2];
    const float* ct    = (const float*)d_in[3];
    const float* W1    = (const float*)d_in[4];
    const float* b1    = (const float*)d_in[5];
    const float* W2    = (const float*)d_in[6];
    const float* b2    = (const float*)d_in[7];
    const float* Wout  = (const float*)d_in[8];
    const float* gamma = (const float*)d_in[9];
    const float* beta  = (const float*)d_in[10];
    float* out = (float*)d_out;

    char* ws = (char*)d_ws;
    unsigned short* W2b = (unsigned short*)(ws);              //  8,388,608 B  [16384][256] bf16
    unsigned short* hbf = (unsigned short*)(ws + 8388608);    //  5,111,808 B  [9984][256] bf16
    float* Qb = (float*)(ws + 13500416);                      //  5,087,232 B  [9936][128] f32
    float* Qp = (float*)(ws + 18587648);                      //  5,087,232 B  [9936][128] f32

    hipLaunchKernelGGL(k_prep, dim3(3290), dim3(256), 0, stream,
                       W2, W2b, xin, ct, W1, b1, b2, hbf, Qb);
    hipLaunchKernelGGL(k_gemm, dim3(78 * 64), dim3(256), 0, stream, W2b, hbf, xin, Qp);
    hipLaunchKernelGGL(k_attn, dim3(828), dim3(256), 0, stream, Qp, Qb, Kenc, Venc,
                       xin, Wout, gamma, beta, out);
}

// Round 7
// 212.711 us; speedup vs baseline: 1.8450x; 1.8450x over previous
//
#include <hip/hip_runtime.h>
#include <hip/hip_bf16.h>

// Problem constants
#define NB    4
#define NP    12          // P1 == P == 12
#define NN_   207
#define DM    128         // d_model
#define DHID  256
#define M_TOK 9936        // NB*NP*NN_
#define M_PAD 9984        // padded to 156*64
#define KSPLIT 8          // j-splits (j-chunk = 32)

typedef float        f32x4 __attribute__((ext_vector_type(4)));
typedef unsigned int u32x4 __attribute__((ext_vector_type(4)));

static __device__ __forceinline__ unsigned int pk_bf2(float a, float b) {
    __hip_bfloat16 ba = __float2bfloat16(a);
    __hip_bfloat16 bb = __float2bfloat16(b);
    unsigned short ua = *reinterpret_cast<unsigned short*>(&ba);
    unsigned short ub = *reinterpret_cast<unsigned short*>(&bb);
    return (unsigned int)ua | ((unsigned int)ub << 16);
}

// ---------------- fused prep kernel: W2->bf16 | transpose x | meta (h, Qb) ----------
// blocks [0,2048): cvt_w2; [2048,3296): transpose; [3296,4538): meta
__global__ __launch_bounds__(256) void k_prep(const float* __restrict__ W2,
                                              unsigned short* __restrict__ W2b,
                                              const float* __restrict__ x,
                                              float* __restrict__ xT,
                                              const float* __restrict__ ct,
                                              const float* __restrict__ W1,
                                              const float* __restrict__ b1,
                                              const float* __restrict__ b2,
                                              float* __restrict__ hbuf,
                                              float* __restrict__ Qb) {
    __shared__ float sm[2112];
    const int t = threadIdx.x;
    const int bid = blockIdx.x;
    if (bid < 2048) {
        // ---- W2 fp32 -> bf16, 8 f32 per thread ----
        int i = bid * 256 + t;
        const f32x4* in = reinterpret_cast<const f32x4*>(W2);
        f32x4 v0 = in[2 * i], v1 = in[2 * i + 1];
        u32x4 o;
        o[0] = pk_bf2(v0[0], v0[1]);
        o[1] = pk_bf2(v0[2], v0[3]);
        o[2] = pk_bf2(v1[0], v1[1]);
        o[3] = pk_bf2(v1[2], v1[3]);
        reinterpret_cast<u32x4*>(W2b)[i] = o;
    } else if (bid < 3296) {
        // ---- transpose inputs -> xT[128][M_PAD], pad m>=M_TOK with 0 ----
        float (*tile)[33] = reinterpret_cast<float (*)[33]>(sm);
        const int b = bid - 2048;
        const int bm = b >> 2;          // 312 m-tiles of 32
        const int bd = b & 3;           // 4 d-tiles of 32
        const int m0 = bm * 32, d0 = bd * 32;
        #pragma unroll
        for (int i = 0; i < 4; ++i) {
            int e = i * 256 + t;
            int lm = e >> 5, ld = e & 31;
            int m = m0 + lm;
            tile[lm][ld] = (m < M_TOK) ? x[(size_t)m * DM + d0 + ld] : 0.0f;
        }
        __syncthreads();
        #pragma unroll
        for (int i = 0; i < 4; ++i) {
            int e = i * 256 + t;
            int ld = e >> 5, lm = e & 31;
            xT[(size_t)(d0 + ld) * M_PAD + m0 + lm] = tile[lm][ld];
        }
    } else {
        // ---- meta: h = relu(W1 ct + b1); Qb = b2-reshaped . x ----
        float* cts = sm;                // [8][128]
        float* xs  = sm + 1024;         // [8][128]
        const int b = bid - 3296;
        const int m0 = b * 8;
        {
            int tok = t >> 5, c4 = t & 31;
            *reinterpret_cast<f32x4*>(&cts[tok * 128 + c4 * 4]) =
                *reinterpret_cast<const f32x4*>(&ct[(size_t)(m0 + tok) * DM + c4 * 4]);
            *reinterpret_cast<f32x4*>(&xs[tok * 128 + c4 * 4]) =
                *reinterpret_cast<const f32x4*>(&x[(size_t)(m0 + tok) * DM + c4 * 4]);
        }
        __syncthreads();
        {   // h: thread t owns hidden unit j = t for 8 tokens
            const int j = t;
            const f32x4* w1r = reinterpret_cast<const f32x4*>(&W1[(size_t)j * DM]);
            float acc[8] = {0, 0, 0, 0, 0, 0, 0, 0};
            for (int c = 0; c < 32; ++c) {
                f32x4 wv = w1r[c];
                #pragma unroll
                for (int tok = 0; tok < 8; ++tok) {
                    f32x4 cv = *reinterpret_cast<const f32x4*>(&cts[tok * 128 + c * 4]);
                    acc[tok] += wv[0] * cv[0] + wv[1] * cv[1] + wv[2] * cv[2] + wv[3] * cv[3];
                }
            }
            float bb = b1[j];
            #pragma unroll
            for (int tok = 0; tok < 8; ++tok)
                hbuf[(size_t)(m0 + tok) * DHID + j] = fmaxf(acc[tok] + bb, 0.0f);
        }
        {   // Qb: thread owns output o = t&127 for 4 tokens
            const int o = t & 127;
            const int tg = (t >> 7) * 4;
            const f32x4* b2r = reinterpret_cast<const f32x4*>(&b2[(size_t)o * DM]);
            float acc[4] = {0, 0, 0, 0};
            for (int c = 0; c < 32; ++c) {
                f32x4 wv = b2r[c];
                #pragma unroll
                for (int tt = 0; tt < 4; ++tt) {
                    f32x4 xv = *reinterpret_cast<const f32x4*>(&xs[(tg + tt) * 128 + c * 4]);
                    acc[tt] += wv[0] * xv[0] + wv[1] * xv[1] + wv[2] * xv[2] + wv[3] * xv[3];
                }
            }
            #pragma unroll
            for (int tt = 0; tt < 4; ++tt)
                Qb[(size_t)(m0 + tg + tt) * DM + o] = acc[tt];
        }
    }
}

// ---------------- kernel: bilinear GEMM (bf16 MFMA), dbuf + XOR swizzle ----------------
// (round-2 verified version: 121 us, 0 bank conflicts)
__global__ __launch_bounds__(256, 4) void k_gemm(const unsigned short* __restrict__ W2b,
                                                 const float* __restrict__ hbuf,
                                                 const float* __restrict__ xT,
                                                 float* __restrict__ Qp) {
    __shared__ unsigned short As[2][64 * 32];    // 4KB each
    __shared__ unsigned short Bs[2][128 * 32];   // 8KB each
    const int t = threadIdx.x;
    const int kid = blockIdx.x & 7;      // j-split -> XCD (round-robin dispatch)
    const int mb  = blockIdx.x >> 3;
    const int m0 = mb * 64;
    const int j0 = kid * 32;
    const int w = t >> 6;                // wave 0..3 owns o-range w*32
    const int l = t & 63;
    const int obase = w * 32;
    const int ro = t >> 2;               // staging row 0..63
    const int c2 = t & 3;                // staging granule

    // h fragment in registers (row m0+ro, j-chunk), reused for all 128 d-steps
    const float* hrow = &hbuf[(size_t)(m0 + ro) * DHID + j0 + c2 * 8];
    const f32x4 ha  = *reinterpret_cast<const f32x4*>(hrow);
    const f32x4 hb4 = *reinterpret_cast<const f32x4*>(hrow + 4);

    f32x4 acc[4][2];
    #pragma unroll
    for (int mt = 0; mt < 4; ++mt) {
        acc[mt][0] = (f32x4)(0.0f);
        acc[mt][1] = (f32x4)(0.0f);
    }

    // LDS write offset (shorts), same swizzle for As row ro and Bs rows ro / ro+64
    const int awOff = ro * 32 + ((c2 ^ ((ro >> 1) & 3)) * 8);
    // LDS read base (shorts): row = <tile>*16 + lr, granule g = l>>4
    const int lr = l & 15;
    const int g  = l >> 4;
    const int aBase = lr * 32 + ((g ^ ((lr >> 1) & 3)) * 8);

    const unsigned short* Bsrc = W2b + (size_t)j0 + c2 * 8;
    const size_t boff0 = (size_t)ro * 32768;
    const size_t boff1 = (size_t)(64 + ro) * 32768;

#define STAGE(BUF, BV0, BV1, XV) do {                            \
        u32x4 av_;                                               \
        av_[0] = pk_bf2((XV) * ha[0],  (XV) * ha[1]);            \
        av_[1] = pk_bf2((XV) * ha[2],  (XV) * ha[3]);            \
        av_[2] = pk_bf2((XV) * hb4[0], (XV) * hb4[1]);           \
        av_[3] = pk_bf2((XV) * hb4[2], (XV) * hb4[3]);           \
        *reinterpret_cast<u32x4*>(&As[BUF][awOff]) = av_;        \
        *reinterpret_cast<u32x4*>(&Bs[BUF][awOff]) = (BV0);      \
        *reinterpret_cast<u32x4*>(&Bs[BUF][awOff + 2048]) = (BV1); \
    } while (0)

    // prologue: stage d=0 into buf0; prefetch d=1
    {
        u32x4 bv0 = *reinterpret_cast<const u32x4*>(Bsrc + boff0);
        u32x4 bv1 = *reinterpret_cast<const u32x4*>(Bsrc + boff1);
        float xv  = xT[m0 + ro];
        STAGE(0, bv0, bv1, xv);
    }
    u32x4 nbv0 = *reinterpret_cast<const u32x4*>(Bsrc + boff0 + 256);
    u32x4 nbv1 = *reinterpret_cast<const u32x4*>(Bsrc + boff1 + 256);
    float nxv  = xT[(size_t)M_PAD + m0 + ro];
    __syncthreads();

    int cur = 0;
    for (int d = 0; d < 128; ++d) {
        // read fragments of current tile
        u32x4 afr0 = *reinterpret_cast<const u32x4*>(&As[cur][aBase]);
        u32x4 afr1 = *reinterpret_cast<const u32x4*>(&As[cur][aBase + 512]);
        u32x4 afr2 = *reinterpret_cast<const u32x4*>(&As[cur][aBase + 1024]);
        u32x4 afr3 = *reinterpret_cast<const u32x4*>(&As[cur][aBase + 1536]);
        u32x4 bfr0 = *reinterpret_cast<const u32x4*>(&Bs[cur][obase * 32 + aBase]);
        u32x4 bfr1 = *reinterpret_cast<const u32x4*>(&Bs[cur][obase * 32 + 512 + aBase]);
        // stage next tile into the other buffer (overlaps with MFMA below)
        if (d < 127) STAGE(cur ^ 1, nbv0, nbv1, nxv);
        // prefetch d+2 from global
        if (d < 126) {
            nbv0 = *reinterpret_cast<const u32x4*>(Bsrc + boff0 + (size_t)(d + 2) * 256);
            nbv1 = *reinterpret_cast<const u32x4*>(Bsrc + boff1 + (size_t)(d + 2) * 256);
            nxv  = xT[(size_t)(d + 2) * M_PAD + m0 + ro];
        }
        __builtin_amdgcn_s_setprio(1);
        asm("v_mfma_f32_16x16x32_bf16 %0, %1, %2, %0" : "+v"(acc[0][0]) : "v"(afr0), "v"(bfr0));
        asm("v_mfma_f32_16x16x32_bf16 %0, %1, %2, %0" : "+v"(acc[0][1]) : "v"(afr0), "v"(bfr1));
        asm("v_mfma_f32_16x16x32_bf16 %0, %1, %2, %0" : "+v"(acc[1][0]) : "v"(afr1), "v"(bfr0));
        asm("v_mfma_f32_16x16x32_bf16 %0, %1, %2, %0" : "+v"(acc[1][1]) : "v"(afr1), "v"(bfr1));
        asm("v_mfma_f32_16x16x32_bf16 %0, %1, %2, %0" : "+v"(acc[2][0]) : "v"(afr2), "v"(bfr0));
        asm("v_mfma_f32_16x16x32_bf16 %0, %1, %2, %0" : "+v"(acc[2][1]) : "v"(afr2), "v"(bfr1));
        asm("v_mfma_f32_16x16x32_bf16 %0, %1, %2, %0" : "+v"(acc[3][0]) : "v"(afr3), "v"(bfr0));
        asm("v_mfma_f32_16x16x32_bf16 %0, %1, %2, %0" : "+v"(acc[3][1]) : "v"(afr3), "v"(bfr1));
        __builtin_amdgcn_s_setprio(0);
        __syncthreads();
        cur ^= 1;
    }
#undef STAGE

    // epilogue: D layout col(o) = lane&15, row(m) = (lane>>4)*4 + reg
    float* outp = Qp + (size_t)kid * M_PAD * DM;
    #pragma unroll
    for (int mt = 0; mt < 4; ++mt)
        #pragma unroll
        for (int ot = 0; ot < 2; ++ot)
            #pragma unroll
            for (int r = 0; r < 4; ++r) {
                int m = m0 + mt * 16 + g * 4 + r;
                int o = obase + ot * 16 + lr;
                outp[(size_t)m * DM + o] = acc[mt][ot][r];
            }
}

// ---------------- attention + W_out(global-stream) + residual + layernorm ----------------
__global__ __launch_bounds__(256) void k_attn(const float* __restrict__ Qp,
                                              const float* __restrict__ Qb,
                                              const float* __restrict__ Kenc,
                                              const float* __restrict__ Venc,
                                              const float* __restrict__ xin,
                                              const float* __restrict__ Wout,
                                              const float* __restrict__ gamma,
                                              const float* __restrict__ beta,
                                              float* __restrict__ out) {
    __shared__ float Qs[12][132];
    __shared__ float Ks[12][132];
    __shared__ float Vs[12][132];
    __shared__ float Ss[12][12][8];
    __shared__ float Os[12][132];
    const int t = threadIdx.x;
    const int b = blockIdx.x / NN_;
    const int n = blockIdx.x % NN_;

    // stage Q (sum of 8 partials + bias term), K, V
    for (int e = t; e < 384; e += 256) {
        int row = e >> 5, c4 = e & 31;
        size_t mrow = (size_t)(b * NP + row) * NN_ + n;
        f32x4 q = *reinterpret_cast<const f32x4*>(&Qb[mrow * DM + c4 * 4]);
        #pragma unroll
        for (int k = 0; k < KSPLIT; ++k)
            q += *reinterpret_cast<const f32x4*>(&Qp[((size_t)k * M_PAD + mrow) * DM + c4 * 4]);
        *reinterpret_cast<f32x4*>(&Qs[row][c4 * 4]) = q;
        *reinterpret_cast<f32x4*>(&Ks[row][c4 * 4]) =
            *reinterpret_cast<const f32x4*>(&Kenc[mrow * DM + c4 * 4]);
        *reinterpret_cast<f32x4*>(&Vs[row][c4 * 4]) =
            *reinterpret_cast<const f32x4*>(&Venc[mrow * DM + c4 * 4]);
    }
    __syncthreads();
    // scores
    if (t < 144) {
        int q = t / 12, p = t % 12;
        #pragma unroll
        for (int hh = 0; hh < 8; ++hh) {
            const f32x4* qv = reinterpret_cast<const f32x4*>(&Qs[q][hh * 16]);
            const f32x4* kv = reinterpret_cast<const f32x4*>(&Ks[p][hh * 16]);
            float s = 0.0f;
            #pragma unroll
            for (int c = 0; c < 4; ++c) {
                f32x4 a = qv[c], bb = kv[c];
                s += a[0] * bb[0] + a[1] * bb[1] + a[2] * bb[2] + a[3] * bb[3];
            }
            Ss[q][p][hh] = s * 0.25f;
        }
    }
    __syncthreads();
    // softmax over p
    if (t < 96) {
        int q = t >> 3, hh = t & 7;
        float mx = -1e30f;
        #pragma unroll
        for (int p = 0; p < 12; ++p) mx = fmaxf(mx, Ss[q][p][hh]);
        float ev[12]; float sum = 0.0f;
        #pragma unroll
        for (int p = 0; p < 12; ++p) { ev[p] = __expf(Ss[q][p][hh] - mx); sum += ev[p]; }
        float inv = 1.0f / sum;
        #pragma unroll
        for (int p = 0; p < 12; ++p) Ss[q][p][hh] = ev[p] * inv;
    }
    __syncthreads();
    // PV
    #pragma unroll
    for (int i = 0; i < 6; ++i) {
        int e = i * 256 + t;
        int q = e >> 7, hk = e & 127, hh = hk >> 4;
        float acc = 0.0f;
        #pragma unroll
        for (int p = 0; p < 12; ++p) acc += Ss[q][p][hh] * Vs[p][hk];
        Os[q][hk] = acc;
    }
    __syncthreads();
    // projection: thread owns output col o = t&127 for 6 q-rows; W_out row streamed
    // from global (64KB, L2-resident, shared by all blocks); Os reads are LDS broadcasts.
    {
        const int o  = t & 127;
        const int qh = (t >> 7) * 6;           // 0 or 6
        const f32x4* wrow = reinterpret_cast<const f32x4*>(&Wout[(size_t)o * DM]);
        float pacc[6] = {0, 0, 0, 0, 0, 0};
        for (int c = 0; c < 32; ++c) {
            f32x4 wv = wrow[c];
            #pragma unroll
            for (int qq = 0; qq < 6; ++qq) {
                f32x4 ov = *reinterpret_cast<const f32x4*>(&Os[qh + qq][c * 4]);
                pacc[qq] += wv[0] * ov[0] + wv[1] * ov[1] + wv[2] * ov[2] + wv[3] * ov[3];
            }
        }
        #pragma unroll
        for (int qq = 0; qq < 6; ++qq) {
            size_t mrow = (size_t)(b * NP + qh + qq) * NN_ + n;
            Qs[qh + qq][o] = pacc[qq] + xin[mrow * DM + o];
        }
    }
    __syncthreads();
    // layernorm per row
    const int wv_ = t >> 6, l = t & 63;
    for (int rq = wv_; rq < 12; rq += 4) {
        float v0 = Qs[rq][l], v1 = Qs[rq][l + 64];
        float s = v0 + v1, ss = v0 * v0 + v1 * v1;
        #pragma unroll
        for (int msk = 1; msk < 64; msk <<= 1) {
            s += __shfl_xor(s, msk, 64);
            ss += __shfl_xor(ss, msk, 64);
        }
        float mu = s * (1.0f / 128.0f);
        float var = ss * (1.0f / 128.0f) - mu * mu;
        float rs = rsqrtf(var + 1e-5f);
        size_t mrow = (size_t)(b * NP + rq) * NN_ + n;
        out[mrow * DM + l]      = (v0 - mu) * rs * gamma[l] + beta[l];
        out[mrow * DM + l + 64] = (v1 - mu) * rs * gamma[l + 64] + beta[l + 64];
    }
}

// ---------------- launcher ----------------
extern "C" void kernel_launch(void* const* d_in, const int* in_sizes, int n_in,
                              void* d_out, int out_size, void* d_ws, size_t ws_size,
                              hipStream_t stream) {
    const float* xin   = (const float*)d_in[0];
    const float* Kenc  = (const float*)d_in[1];
    const float* Venc  = (const float*)d_in[2];
    const float* ct    = (const float*)d_in[3];
    const float* W1    = (const float*)d_in[4];
    const float* b1    = (const float*)d_in[5];
    const float* W2    = (const float*)d_in[6];
    const float* b2    = (const float*)d_in[7];
    const float* Wout  = (const float*)d_in[8];
    const float* gamma = (const float*)d_in[9];
    const float* beta  = (const float*)d_in[10];
    float* out = (float*)d_out;

    char* ws = (char*)d_ws;
    unsigned short* W2b = (unsigned short*)(ws);                  //  8,388,608 B
    float* xT  = (float*)(ws + 8388608);                          //  5,111,808 B
    float* hb  = (float*)(ws + 13500416);                         // 10,223,616 B
    float* Qb  = (float*)(ws + 23724032);                         //  5,111,808 B
    float* Qp  = (float*)(ws + 28835840);                         // 40,894,464 B

    hipLaunchKernelGGL(k_prep, dim3(4538), dim3(256), 0, stream,
                       W2, W2b, xin, xT, ct, W1, b1, b2, hb, Qb);
    hipLaunchKernelGGL(k_gemm, dim3(1248), dim3(256), 0, stream, W2b, hb, xT, Qp);
    hipLaunchKernelGGL(k_attn, dim3(828),  dim3(256), 0, stream, Qp, Qb, Kenc, Venc,
                       xin, Wout, gamma, beta, out);
}